// Round 2
// baseline (13380.214 us; speedup 1.0000x reference)
//
#include <hip/hip_runtime.h>
#include <hip/hip_bf16.h>

// MultiLayerLSTM on MI355X: persistent pipelined 2-layer LSTM.
// fp16 MFMA 16x16x32, weights register-resident, cross-block flag sync.

typedef _Float16 f16;
typedef __attribute__((ext_vector_type(8))) _Float16 f16x8;
typedef __attribute__((ext_vector_type(4))) _Float16 f16x4;
typedef __attribute__((ext_vector_type(4))) float f32x4;

#define T_STEPS 2048

// ---------------- prep kernels ----------------

// f32 -> f16 convert of input_seq (layout preserved [B][T][I])
__global__ void k_conv_x(const float* __restrict__ x, f16* __restrict__ xf) {
  int i = (blockIdx.x * 256 + threadIdx.x) * 4;
  float4 v = *(const float4*)(x + i);
  f16x4 o; o[0] = (f16)v.x; o[1] = (f16)v.y; o[2] = (f16)v.z; o[3] = (f16)v.w;
  *(f16x4*)(xf + i) = o;
}

// Pack [W_ih; W_hh] columns for block nb (gate g col = g*512 + nb*16 + c) into
// per-(block,wave,kt,nt,lane) fp16 MFMA B-fragment order.
// k map: k = kt*32 + (lane>>4)*8 + j  -- identical map used for A fragments,
// so any HW intra-lane k permutation cancels in the MFMA dot product.
template<int KTW, int KI>
__global__ void k_pack(const float* __restrict__ wih, const float* __restrict__ whh,
                       f16* __restrict__ dst) {
  int chunk = blockIdx.x * 256 + threadIdx.x;   // one 8-elem fragment per thread
  int lane = chunk & 63;
  int x = chunk >> 6;
  int nt = x & 3; x >>= 2;
  int ktl = x % KTW; x /= KTW;
  int w = x & 3; int nb = x >> 2;
  int k0 = (w * KTW + ktl) * 32 + ((lane >> 4) * 8);
  int cl = nt * 16 + (lane & 15);
  int wcol = (cl >> 4) * 512 + nb * 16 + (cl & 15);
  f16x8 v;
#pragma unroll
  for (int j = 0; j < 8; ++j) {
    int k = k0 + j;
    float s = (k < KI) ? wih[(size_t)k * 2048 + wcol]
                       : whh[(size_t)(k - KI) * 2048 + wcol];
    v[j] = (f16)s;
  }
  *(f16x8*)(dst + (size_t)chunk * 8) = v;
}

// init h rings slot0 from h_0, seed step-0 arrival counters
__global__ void k_init(const float* __restrict__ h0in, f16* h0h, f16* h1h,
                       int* flags0, int* flags1) {
  int tid = threadIdx.x;
  for (int i = tid; i < 16384; i += 256) {
    h0h[i] = (f16)h0in[i];            // layer0 h_0  [32][512]
    h1h[i] = (f16)h0in[16384 + i];    // layer1 h_0
  }
  if (tid < 4) { flags0[tid] = 8; flags1[tid] = 8; }
}

// ---------------- persistent recurrence ----------------

__device__ __forceinline__ void wait_group(int* f) {
  for (;;) {
    int a = __hip_atomic_load(f + 0, __ATOMIC_RELAXED, __HIP_MEMORY_SCOPE_AGENT);
    int b = __hip_atomic_load(f + 1, __ATOMIC_RELAXED, __HIP_MEMORY_SCOPE_AGENT);
    int c = __hip_atomic_load(f + 2, __ATOMIC_RELAXED, __HIP_MEMORY_SCOPE_AGENT);
    int d = __hip_atomic_load(f + 3, __ATOMIC_RELAXED, __HIP_MEMORY_SCOPE_AGENT);
    if (a >= 8 && b >= 8 && c >= 8 && d >= 8) return;
    __builtin_amdgcn_s_sleep(2);
  }
}

template<int LAYER>
__device__ __forceinline__ void lstm_body(
    int nb, float* red,
    const f16* __restrict__ xf, f16* h0h, f16* h1h,
    const f16* __restrict__ wp, const float* __restrict__ bias,
    const float* __restrict__ c0, float* out,
    int* flags0, int* flags1)
{
  constexpr int KTW = (LAYER == 0) ? 6 : 8;   // kt tiles per wave (K=768 / 1024)
  const int tid = threadIdx.x;
  const int w = tid >> 6;
  const int lane = tid & 63;
  const int rowA = lane & 15;
  const int ko = (lane >> 4) * 8;

  // ---- weights -> registers (per wave: its K-slice x all 4 n-tiles)
  f16x8 wf[KTW][4];
  {
    const f16* base = wp + (size_t)((nb * 4 + w) * KTW) * (4 * 64 * 8);
#pragma unroll
    for (int ktl = 0; ktl < KTW; ++ktl)
#pragma unroll
      for (int nt = 0; nt < 4; ++nt)
        wf[ktl][nt] = *(const f16x8*)(base + ((ktl * 4 + nt) * 64 + lane) * 8);
  }

  // ---- elementwise ownership: thread owns 2 of the block's 512 (row,hc) cells
  float creg[2], bgate[2][4], hlast[2];
#pragma unroll
  for (int s = 0; s < 2; ++s) {
    int idx = tid + 256 * s, row = idx >> 4, hc = idx & 15;
    creg[s] = c0[(LAYER * 32 + row) * 512 + nb * 16 + hc];
    hlast[s] = 0.f;
#pragma unroll
    for (int g = 0; g < 4; ++g) bgate[s][g] = bias[g * 512 + nb * 16 + hc];
  }

  const int group = nb >> 3;
  int* myflags = (LAYER == 0) ? flags0 : flags1;

  for (int t = 1; t <= T_STEPS; ++t) {
    // ---- wait for dependencies (tid0 spins, acquire, barrier broadcasts)
    if (tid == 0) {
      if (LAYER == 0) {
        wait_group(flags0 + (t - 1) * 4);
        if (t > 16) wait_group(flags1 + (t - 16) * 4);  // bound L0 lead: h0 ring safety
      } else {
        wait_group(flags0 + t * 4);
        wait_group(flags1 + (t - 1) * 4);
      }
      __builtin_amdgcn_fence(__ATOMIC_ACQUIRE, "agent");
    }
    __syncthreads();

    const int slot0p = ((t - 1) & 15) * 16384;
    const int slot0c = (t & 15) * 16384;
    const int slot1p = ((t - 1) & 3) * 16384;

    f32x4 acc[2][4];
#pragma unroll
    for (int mt = 0; mt < 2; ++mt)
#pragma unroll
      for (int nt = 0; nt < 4; ++nt)
        acc[mt][nt] = (f32x4){0.f, 0.f, 0.f, 0.f};

    // ---- K-split MFMA: A fragments straight from global (L2/L3 resident)
#pragma unroll
    for (int ktl = 0; ktl < KTW; ++ktl) {
      const int k0 = (w * KTW + ktl) * 32 + ko;
      f16x8 a[2];
#pragma unroll
      for (int mt = 0; mt < 2; ++mt) {
        const int r = mt * 16 + rowA;
        const f16* p;
        if (LAYER == 0) {
          p = (k0 < 256)
            ? xf + (size_t)r * (T_STEPS * 256) + (size_t)(t - 1) * 256 + k0
            : h0h + slot0p + r * 512 + (k0 - 256);
        } else {
          p = (k0 < 512)
            ? h0h + slot0c + r * 512 + k0
            : h1h + slot1p + r * 512 + (k0 - 512);
        }
        a[mt] = *(const f16x8*)p;
      }
#pragma unroll
      for (int nt = 0; nt < 4; ++nt) {
        acc[0][nt] = __builtin_amdgcn_mfma_f32_16x16x32_f16(a[0], wf[ktl][nt], acc[0][nt], 0, 0, 0);
        acc[1][nt] = __builtin_amdgcn_mfma_f32_16x16x32_f16(a[1], wf[ktl][nt], acc[1][nt], 0, 0, 0);
      }
    }

    // ---- cross-wave K reduction through LDS
#pragma unroll
    for (int mt = 0; mt < 2; ++mt)
#pragma unroll
      for (int nt = 0; nt < 4; ++nt)
        *(f32x4*)&red[((((w * 2 + mt) * 4 + nt) * 64) + lane) * 4] = acc[mt][nt];
    __syncthreads();

    // ---- gates + state update (C/D layout: col=lane&15, row=(lane>>4)*4+reg)
#pragma unroll
    for (int s = 0; s < 2; ++s) {
      int idx = tid + 256 * s, row = idx >> 4, hc = idx & 15;
      int mt = row >> 4, rg = (row & 15) >> 2, rr = row & 3;
      float gv[4];
#pragma unroll
      for (int g = 0; g < 4; ++g) {
        float v = bgate[s][g];
#pragma unroll
        for (int ww = 0; ww < 4; ++ww)
          v += red[((((ww * 2 + mt) * 4 + g) * 64) + rg * 16 + hc) * 4 + rr];
        gv[g] = v;
      }
      float ig = 1.f / (1.f + __expf(-gv[0]));
      float fg = 1.f / (1.f + __expf(-gv[1]));
      float gg = tanhf(gv[2]);
      float og = 1.f / (1.f + __expf(-gv[3]));
      float c = fg * creg[s] + ig * gg;
      creg[s] = c;
      float h = og * tanhf(c);
      hlast[s] = h;
      int col = nb * 16 + hc;
      if (LAYER == 0) {
        h0h[slot0c + row * 512 + col] = (f16)h;
      } else {
        h1h[(t & 3) * 16384 + row * 512 + col] = (f16)h;
        __builtin_nontemporal_store(h, out + (size_t)row * (T_STEPS * 512) + (size_t)(t - 1) * 512 + col);
      }
    }

    // ---- publish: drain stores (syncthreads waits vmcnt0), release, arrive
    __syncthreads();
    if (tid == 0) {
      __builtin_amdgcn_fence(__ATOMIC_RELEASE, "agent");
      __hip_atomic_fetch_add(myflags + t * 4 + group, 1, __ATOMIC_RELAXED, __HIP_MEMORY_SCOPE_AGENT);
    }
  }

  // ---- final h_T, c_T (layer 1 only)
  if (LAYER == 1) {
#pragma unroll
    for (int s = 0; s < 2; ++s) {
      int idx = tid + 256 * s, row = idx >> 4, hc = idx & 15;
      int col = nb * 16 + hc;
      out[(size_t)(32 * T_STEPS * 512) + row * 512 + col] = hlast[s];
      out[(size_t)(32 * T_STEPS * 512) + 16384 + row * 512 + col] = creg[s];
    }
  }
}

__global__ __launch_bounds__(256, 1) void lstm_persist(
    const f16* __restrict__ xf, f16* h0h, f16* h1h,
    const f16* __restrict__ wp0, const f16* __restrict__ wp1,
    const float* __restrict__ b0, const float* __restrict__ b1,
    const float* __restrict__ c0, float* out,
    int* flags0, int* flags1)
{
  __shared__ float red[4 * 2 * 4 * 64 * 4];   // 32 KB
  int bid = blockIdx.x;
  if (bid < 32)
    lstm_body<0>(bid, red, xf, h0h, h1h, wp0, b0, c0, out, flags0, flags1);
  else
    lstm_body<1>(bid - 32, red, xf, h0h, h1h, wp1, b1, c0, out, flags0, flags1);
}

// ---------------- launch ----------------

extern "C" void kernel_launch(void* const* d_in, const int* in_sizes, int n_in,
                              void* d_out, int out_size, void* d_ws, size_t ws_size,
                              hipStream_t stream) {
  const float* x    = (const float*)d_in[0];
  const float* h0   = (const float*)d_in[1];
  const float* c0   = (const float*)d_in[2];
  const float* Wih0 = (const float*)d_in[3];
  const float* Whh0 = (const float*)d_in[4];
  const float* b0   = (const float*)d_in[5];
  const float* Wih1 = (const float*)d_in[6];
  const float* Whh1 = (const float*)d_in[7];
  const float* b1   = (const float*)d_in[8];
  float* out = (float*)d_out;
  char* ws = (char*)d_ws;

  // ws layout (bytes), total ~41.7 MB
  f16* xf  = (f16*)(ws);                 // 33,554,432  x as fp16 [B][T][I]
  f16* h0h = (f16*)(ws + 33554432);      //    524,288  h0 ring, 16 slots [32][512] f16
  f16* h1h = (f16*)(ws + 34078720);      //    131,072  h1 ring, 4 slots
  f16* wp0 = (f16*)(ws + 34209792);      //  3,145,728  packed [Wih0;Whh0]
  f16* wp1 = (f16*)(ws + 37355520);      //  4,194,304  packed [Wih1;Whh1]
  int* flags0 = (int*)(ws + 41549824);   //     33,024  arrival counters [t][4]
  int* flags1 = (int*)(ws + 41582848);   //     33,024

  hipMemsetAsync(ws + 41549824, 0, 66048, stream);
  k_conv_x<<<16384, 256, 0, stream>>>(x, xf);
  k_pack<6, 256><<<768, 256, 0, stream>>>(Wih0, Whh0, wp0);
  k_pack<8, 512><<<1024, 256, 0, stream>>>(Wih1, Whh1, wp1);
  k_init<<<1, 256, 0, stream>>>(h0, h0h, h1h, flags0, flags1);
  lstm_persist<<<64, 256, 0, stream>>>(xf, h0h, h1h, wp0, wp1, b0, b1, c0, out,
                                       flags0, flags1);
}